// Round 1
// baseline (261.144 us; speedup 1.0000x reference)
//
#include <hip/hip_runtime.h>

#define NN 20000
#define NNP 20096       // padded rows: 314*64
#define NEIGH 12
#define NCRYS 20
#define MT2 1256        // padded M row-tiles of 16
#define NSUB 16         // pooled partial-sum split

typedef __bf16 bf16x8 __attribute__((ext_vector_type(8)));
typedef __bf16 bf16x4 __attribute__((ext_vector_type(4)));
typedef float f32x4 __attribute__((ext_vector_type(4)));
typedef float f32x2 __attribute__((ext_vector_type(2)));

// ============================================================
// pack: W[k][n] -> bf16 MFMA-B frag layout Wp[kt][nt][k8][ni][j]
// ============================================================
__device__ __forceinline__ void pack_one(const float* Wrel, const float* Wroot,
                                         __bf16* Wp, int K, int idx) {
    int k = idx >> 8, n = idx & 255;
    int r = n >> 6, h = n & 63;
    float v = (r < 3) ? Wrel[((size_t)r * K + k) * 64 + h] : Wroot[(size_t)k * 64 + h];
    int kt = k >> 5, k8 = (k >> 3) & 3, j = k & 7, nt = n >> 4, ni = n & 15;
    Wp[((((size_t)kt * 16 + nt) * 4 + k8) * 16 + ni) * 8 + j] = (__bf16)v;
}

// ============================================================
// setup: build_adj (938) + pack (256, strided) + transpose (628)
// ============================================================
__global__ __launch_bounds__(256) void setup_kernel(
    const int* __restrict__ species, const int* __restrict__ nbr,
    int* __restrict__ adj, int* __restrict__ deg,
    const float* __restrict__ W1b_rel, const float* __restrict__ W1b_root,
    const float* __restrict__ W1a_rel, const float* __restrict__ W1a_root,
    const float* __restrict__ W2b_rel, const float* __restrict__ W2b_root,
    const float* __restrict__ W2a_rel, const float* __restrict__ W2a_root,
    __bf16* __restrict__ Wp1b, __bf16* __restrict__ Wp1a,
    __bf16* __restrict__ Wp2b, __bf16* __restrict__ Wp2a,
    const float* __restrict__ bond, const float* __restrict__ angle,
    float* __restrict__ bondT, float* __restrict__ angleT) {
    __shared__ float ls[64 * 145];
    const int bx = blockIdx.x, tid = threadIdx.x;
    if (bx < 938) {
        int e = bx * 256 + tid;
        if (e < NN * NEIGH) {
            int i = e / NEIGH;
            int d = nbr[e];
            int r = species[i] + species[d];
            int slot = atomicAdd(&deg[d], 1);
            if (slot < 64) adj[(size_t)d * 64 + slot] = i | (r << 28);
        }
    } else if (bx < 938 + 256) {
        const int S0 = 480 * 256, S1 = S0 + 2880 * 256, S2 = S1 + 64 * 256, S3 = S2 + 64 * 256;
        for (int idx = (bx - 938) * 256 + tid; idx < S3; idx += 256 * 256) {
            if (idx < S0)       pack_one(W1b_rel, W1b_root, Wp1b, 480, idx);
            else if (idx < S1)  pack_one(W1a_rel, W1a_root, Wp1a, 2880, idx - S0);
            else if (idx < S2)  pack_one(W2b_rel, W2b_root, Wp2b, 64, idx - S1);
            else                pack_one(W2a_rel, W2a_root, Wp2a, 64, idx - S2);
        }
    } else {
        int tb = bx - 1194;
        if (tb < 314) {
            int m0 = tb * 64;
            for (int idx = tid; idx < 64 * 144; idx += 256) {
                int mm = idx / 144, j = idx - mm * 144;
                int m = m0 + mm;
                ls[mm * 145 + j] = (m < NN) ? angle[(size_t)m * 144 + j] : 0.f;
            }
            __syncthreads();
            for (int idx = tid; idx < 144 * 64; idx += 256) {
                int j = idx >> 6, mm = idx & 63;
                angleT[(size_t)j * NNP + m0 + mm] = ls[mm * 145 + j];
            }
        } else {
            int m0 = (tb - 314) * 64;
            for (int idx = tid; idx < 64 * 12; idx += 256) {
                int mm = idx / 12, j = idx - mm * 12;
                int m = m0 + mm;
                ls[mm * 13 + j] = (m < NN) ? bond[(size_t)m * 12 + j] : 0.f;
            }
            __syncthreads();
            for (int idx = tid; idx < 12 * 64; idx += 256) {
                int j = idx >> 6, mm = idx & 63;
                bondT[(size_t)j * NNP + m0 + mm] = ls[mm * 13 + j];
            }
        }
    }
}

// ============================================================
// gemm1: 64x256 tile, 512 threads (8 waves, each 64r x 32c, acc[4][2]).
// 64-K PHASES: two 32-k MFMA tiles per barrier (halves barrier count).
// Bond K padded 480->512 (zeroed Wp1b tail + zeroed bondT pad rows) so
// the schedule is uniform. GBF staging: each thread computes 2 chunks of
// 4 (one per k-tile half) with the exp recurrence as f32x2 packed math
// (v_pk_fma/mul). Loop-carried reg prefetch for B frags and A x-values
// (no v_mov rotation). A: 8KB LDS ping-pong (2x 64x64 bf16).
// ============================================================
template <int MODE>  // 0: bond KPAD=512 DIVN=40; 1: angle K=2880 DIVN=20
__device__ __forceinline__ void gemm1_body(const float* __restrict__ xT,
                                           const __bf16* __restrict__ Wp,
                                           float* __restrict__ Y, int mb,
                                           __bf16* __restrict__ Al) {
    constexpr int KTOT = (MODE == 0) ? 512 : 2880;   // bond padded to 512
    constexpr int NPH = KTOT / 64;
    constexpr int DIVN = (MODE == 0) ? 40 : 20;
    constexpr int ADDJ = 64 / DIVN;
    constexpr int ADDS = 64 % DIVN;
    constexpr float F0 = (MODE == 0) ? 0.f : -1.f;
    constexpr float FS = (MODE == 0) ? (8.f / 39.f) : (2.f / 19.f);
    constexpr float NG2 = ((MODE == 0) ? -25.f : -100.f) * 1.44269504f;  // -gamma^-2*log2e
    const float C  = __builtin_amdgcn_exp2f(2.f * NG2 * FS * FS);
    const float P1 = NG2 * FS * FS;
    const float P2 = -2.f * NG2 * FS;

    const int tid = threadIdx.x;
    const int lane = tid & 63, wv = tid >> 6;
    const int m0 = mb * 64;
    // staging role: thread -> one 4-element chunk per k-tile half
    const int smt = tid >> 7;             // 0..3
    const int sk8 = (tid >> 5) & 3;
    const int smi = (tid >> 1) & 15;
    const int sjh = (tid & 1) * 4;
    const int sgm = m0 + smt * 16 + smi;
    const int kk0 = sk8 * 8 + sjh;        // k-offset within 32-tile, 0..28
    const int swoff = (((smt * 4 + sk8) * 16 + smi) * 8 + sjh);
    // MFMA role
    const int k8b = lane >> 4, nib = lane & 15;
    const bf16x8* Bg = (const bf16x8*)Wp;

    f32x4 acc[4][2] = {};
    bf16x8 bcur[4];

    // incremental (element, offset) state for the two chunks; advances +64/phase
    int jr0 = kk0 / DIVN,        s0 = kk0 % DIVN;
    int jr1 = (32 + kk0) / DIVN, s1 = (32 + kk0) % DIVN;

    auto bload = [&](int ph) {
#pragma unroll
        for (int jf = 0; jf < 4; ++jf)
            bcur[jf] = Bg[(((size_t)(2 * ph + (jf >> 1)) * 16 + 2 * wv + (jf & 1)) * 4 + k8b) * 16 + nib];
    };
    auto advance = [&]() {
        jr0 += ADDJ; s0 += ADDS; if (s0 >= DIVN) { s0 -= DIVN; ++jr0; }
        jr1 += ADDJ; s1 += ADDS; if (s1 >= DIVN) { s1 -= DIVN; ++jr1; }
    };
    auto stage = [&](float a0, float a1, __bf16* dst) {
        f32x2 d;
        d.x = a0 - (F0 + (float)s0 * FS);
        d.y = a1 - (F0 + (float)s1 * FS);
        f32x2 t = d * d;
        f32x2 argE = t * NG2;
        f32x2 argQ = d * P2 + P1;
        f32x2 e0, q0;
        e0.x = __builtin_amdgcn_exp2f(argE.x);
        e0.y = __builtin_amdgcn_exp2f(argE.y);
        q0.x = __builtin_amdgcn_exp2f(argQ.x);
        q0.y = __builtin_amdgcn_exp2f(argQ.y);
        f32x2 e1 = e0 * q0;
        f32x2 q1 = q0 * C;
        f32x2 e2 = e1 * q1;
        f32x2 e3 = e2 * (q1 * C);
        bf16x4 v0, v1;
        v0[0] = (__bf16)e0.x; v0[1] = (__bf16)e1.x; v0[2] = (__bf16)e2.x; v0[3] = (__bf16)e3.x;
        v1[0] = (__bf16)e0.y; v1[1] = (__bf16)e1.y; v1[2] = (__bf16)e2.y; v1[3] = (__bf16)e3.y;
        *(bf16x4*)&dst[swoff] = v0;
        *(bf16x4*)&dst[2048 + swoff] = v1;
    };

    // ---- prologue: stage phase 0, prefetch A(phase1) + B(phase0) ----
    {
        float a0 = xT[(size_t)jr0 * NNP + sgm];
        float a1 = xT[(size_t)jr1 * NNP + sgm];
        stage(a0, a1, Al);
        advance();
    }
    float an0 = xT[(size_t)jr0 * NNP + sgm];
    float an1 = xT[(size_t)jr1 * NNP + sgm];
    bload(0);
    __syncthreads();

    int cur = 0;
    for (int ph = 0; ph < NPH; ++ph) {
        const __bf16* Ab = Al + (cur << 12);
        // ---- MFMA: k-tile 0 of phase ----
        bf16x8 af[4];
#pragma unroll
        for (int t4 = 0; t4 < 4; ++t4)
            af[t4] = *(const bf16x8*)&Ab[((((t4 << 2) + k8b) << 4) + nib) << 3];
#pragma unroll
        for (int i = 0; i < 4; ++i) {
            acc[i][0] = __builtin_amdgcn_mfma_f32_16x16x32_bf16(af[i], bcur[0], acc[i][0], 0, 0, 0);
            acc[i][1] = __builtin_amdgcn_mfma_f32_16x16x32_bf16(af[i], bcur[1], acc[i][1], 0, 0, 0);
        }
        // ---- MFMA: k-tile 1 of phase ----
        bf16x8 ag[4];
#pragma unroll
        for (int t4 = 0; t4 < 4; ++t4)
            ag[t4] = *(const bf16x8*)&Ab[2048 + (((((t4 << 2) + k8b) << 4) + nib) << 3)];
#pragma unroll
        for (int i = 0; i < 4; ++i) {
            acc[i][0] = __builtin_amdgcn_mfma_f32_16x16x32_bf16(ag[i], bcur[2], acc[i][0], 0, 0, 0);
            acc[i][1] = __builtin_amdgcn_mfma_f32_16x16x32_bf16(ag[i], bcur[3], acc[i][1], 0, 0, 0);
        }
        // ---- stage next phase while matrix pipe drains ----
        if (ph + 1 < NPH) {
            bload(ph + 1);                       // loop-carried: consumed next iter
            stage(an0, an1, Al + ((cur ^ 1) << 12));
            advance();
            if (ph + 2 < NPH) {                  // loop-carried A prefetch
                an0 = xT[(size_t)jr0 * NNP + sgm];
                an1 = xT[(size_t)jr1 * NNP + sgm];
            }
        }
        __syncthreads();
        cur ^= 1;
    }

    // ---- epilogue: C/D layout col=lane&15, row=(lane>>4)*4+reg; f32 out ----
    const int mrow0 = m0 + ((lane >> 4) << 2);
    const int ncol = (wv << 5) + nib;
#pragma unroll
    for (int i = 0; i < 4; ++i)
#pragma unroll
        for (int j = 0; j < 2; ++j)
#pragma unroll
            for (int v = 0; v < 4; ++v) {
                int m = mrow0 + i * 16 + v;
                if (m < NN) Y[(size_t)m * 256 + ncol + j * 16] = acc[i][j][v];
            }
}

__global__ __launch_bounds__(512, 4) void mega_gemm1(const float* __restrict__ bondT,
                                                     const float* __restrict__ angleT,
                                                     const __bf16* __restrict__ Wp1b,
                                                     const __bf16* __restrict__ Wp1a,
                                                     float* __restrict__ Yb, float* __restrict__ Ya) {
    __shared__ __align__(16) __bf16 Al[2 * 4096];
    int bx = blockIdx.x;
    if (bx < 314) gemm1_body<1>(angleT, Wp1a, Ya, bx, Al);
    else          gemm1_body<0>(bondT, Wp1b, Yb, bx - 314, Al);
}

// ============================================================
// Dense layer-2 GEMM, both chains. K=64, A pre-packed bf16, f32 out
// ============================================================
__global__ __launch_bounds__(256) void mega_gemm2(const __bf16* __restrict__ Hbp,
                                                  const __bf16* __restrict__ Hap,
                                                  const __bf16* __restrict__ Wp2b,
                                                  const __bf16* __restrict__ Wp2a,
                                                  float* __restrict__ Yb, float* __restrict__ Ya) {
    __shared__ __align__(16) __bf16 Al[4096];
    __shared__ __align__(16) __bf16 Bl[4096];
    const int ch = blockIdx.x & 1;
    const int mb = blockIdx.x >> 1;
    const int nb = blockIdx.y;
    const __bf16* Ap = ch ? Hap : Hbp;
    const __bf16* Wp = ch ? Wp2a : Wp2b;
    float* Y = ch ? Ya : Yb;
    const int tid = threadIdx.x;
    const int lane = tid & 63, wv = tid >> 6;
    const int m0 = mb * 128;
    const int rw = wv & 1, cw = wv >> 1;
    f32x4 acc[4][4] = {};
#pragma unroll
    for (int kt = 0; kt < 2; ++kt) {
        __syncthreads();
        {
            const float4* src = (const float4*)(Wp + (((size_t)kt * 16 + nb * 8) << 9));
            float4* dst = (float4*)Bl;
            float4 v0 = src[tid], v1 = src[tid + 256];
            dst[tid] = v0;
            dst[tid + 256] = v1;
        }
        {
            const float4* src = (const float4*)(Ap + (((size_t)kt * MT2 + mb * 8) << 9));
            float4* dst = (float4*)Al;
            float4 v0 = src[tid], v1 = src[tid + 256];
            dst[tid] = v0;
            dst[tid + 256] = v1;
        }
        __syncthreads();
        bf16x8 af[4], bfr[4];
        int fro = ((lane >> 4) << 4) + (lane & 15);
#pragma unroll
        for (int t4 = 0; t4 < 4; ++t4) {
            af[t4] = *(const bf16x8*)&Al[((((rw * 4 + t4) << 6) + fro) << 3)];
            bfr[t4] = *(const bf16x8*)&Bl[((((cw * 4 + t4) << 6) + fro) << 3)];
        }
#pragma unroll
        for (int i = 0; i < 4; ++i)
#pragma unroll
            for (int j = 0; j < 4; ++j)
                acc[i][j] = __builtin_amdgcn_mfma_f32_16x16x32_bf16(af[i], bfr[j], acc[i][j], 0, 0, 0);
    }
    const int n0 = nb * 128 + cw * 64;
    const int mrow0 = m0 + rw * 64 + ((lane >> 4) << 2);
    const int ncol = n0 + (lane & 15);
#pragma unroll
    for (int i = 0; i < 4; ++i)
#pragma unroll
        for (int j = 0; j < 4; ++j)
#pragma unroll
            for (int v = 0; v < 4; ++v) {
                int m = mrow0 + i * 16 + v;
                if (m < NN) Y[(size_t)m * 256 + ncol + j * 16] = acc[i][j][v];
            }
}

// ============================================================
// agg core: scalar (readlane) addresses + 16-batched gathers -> one
// latency wall per batch instead of a serialized shfl chain.
// ============================================================
__device__ __forceinline__ float agg_node(const float* __restrict__ Y,
                                          const int* __restrict__ adj,
                                          const int* __restrict__ deg,
                                          const float* __restrict__ bias,
                                          int node, int h) {
    int dg = min(deg[node], 64);
    int e = adj[(size_t)node * 64 + h];  // lane h holds edge h
    bool val = h < dg;
    int r = e >> 28;
    unsigned long long bl0 = __ballot(val && r == 0);
    unsigned long long bl1 = __ballot(val && r == 1);
    unsigned long long bl2 = __ballot(val && r == 2);
    int c0 = __popcll(bl0), c1 = __popcll(bl1), c2 = __popcll(bl2);
    float s0 = 0.f, s1 = 0.f, s2 = 0.f;
    if (dg > 0) {
        int e0 = __builtin_amdgcn_readfirstlane(e);
        int ec = val ? e : e0;  // clamp garbage lanes to a valid edge
        for (int k0 = 0; k0 < dg; k0 += 16) {
            float v[16];
#pragma unroll
            for (int i = 0; i < 16; ++i) {
                int ek = __builtin_amdgcn_readlane(ec, k0 + i);  // SGPR
                v[i] = Y[(size_t)(ek & 0x0FFFFFFF) * 256 + (ek >> 28) * 64 + h];
            }
#pragma unroll
            for (int i = 0; i < 16; ++i) {
                int kk = k0 + i;
                if (kk < dg) {  // wave-uniform
                    int rr = __builtin_amdgcn_readlane(ec, kk) >> 28;
                    if (rr == 0) s0 += v[i];
                    else if (rr == 1) s1 += v[i];
                    else s2 += v[i];
                }
            }
        }
    }
    float o = Y[(size_t)node * 256 + 192 + h] + bias[h] +
              s0 / fmaxf((float)c0, 1.f) + s1 / fmaxf((float)c1, 1.f) +
              s2 / fmaxf((float)c2, 1.f);
    return fmaxf(o, 0.f);
}

// layer-1 agg -> bf16 packed-A frag layout (feeds mega_gemm2)
__global__ __launch_bounds__(256) void agg_packed(const float* __restrict__ Yb,
                                                  const float* __restrict__ Ya,
                                                  const int* __restrict__ adj,
                                                  const int* __restrict__ deg,
                                                  const float* __restrict__ biasb,
                                                  const float* __restrict__ biasa,
                                                  __bf16* __restrict__ outb,
                                                  __bf16* __restrict__ outa) {
    const float* Y = blockIdx.y ? Ya : Yb;
    const float* bias = blockIdx.y ? biasa : biasb;
    __bf16* outp = blockIdx.y ? outa : outb;
    int node = blockIdx.x * 4 + (threadIdx.x >> 6);
    int h = threadIdx.x & 63;
    float o = (node < NN) ? agg_node(Y, adj, deg, bias, node, h) : 0.f;
    int mt = node >> 4, mi = node & 15;
    int ktt = h >> 5, k8 = (h >> 3) & 3, j = h & 7;
    outp[((((size_t)ktt * MT2 + mt) * 4 + k8) * 16 + mi) * 8 + j] = (__bf16)o;
}

// layer-2 agg fused with crystal pooling
__global__ __launch_bounds__(256) void agg_pool(const float* __restrict__ Yb,
                                                const float* __restrict__ Ya,
                                                const int* __restrict__ adj,
                                                const int* __restrict__ deg,
                                                const float* __restrict__ biasb,
                                                const float* __restrict__ biasa,
                                                const int* __restrict__ crys,
                                                float* __restrict__ pooled) {
    const float* Y = blockIdx.y ? Ya : Yb;
    const float* bias = blockIdx.y ? biasa : biasb;
    const int base = blockIdx.y ? 64 : 0;
    int node = blockIdx.x * 4 + (threadIdx.x >> 6);
    int h = threadIdx.x & 63;
    if (node >= NN) return;
    float o = agg_node(Y, adj, deg, bias, node, h);
    int c = 0;
#pragma unroll
    for (int t = 1; t < NCRYS; ++t) c += (node >= crys[t * 2]) ? 1 : 0;
    int sub = blockIdx.x & (NSUB - 1);
    atomicAdd(&pooled[((size_t)c * NSUB + sub) * 128 + base + h], o);
}

// ============================================================
// final: reduce partials, divide by count, FC
// ============================================================
__global__ void final2(const float* __restrict__ pooled, const int* __restrict__ crys,
                       const float* __restrict__ fcW, const float* __restrict__ fcb,
                       float* __restrict__ out) {
    int c = blockIdx.x >> 1, o = blockIdx.x & 1;
    int l = threadIdx.x;  // 0..63
    float cnt = (float)(crys[c * 2 + 1] - crys[c * 2]);
    float sb = 0.f, sa = 0.f;
    for (int s = 0; s < NSUB; ++s) {
        sb += pooled[((size_t)c * NSUB + s) * 128 + l];
        sa += pooled[((size_t)c * NSUB + s) * 128 + 64 + l];
    }
    float a = sb * fcW[l * 2 + o] + sa * fcW[(64 + l) * 2 + o];
    for (int s = 32; s > 0; s >>= 1) a += __shfl_down(a, s);
    if (l == 0) out[c * 2 + o] = a / cnt + fcb[o];
}

extern "C" void kernel_launch(void* const* d_in, const int* in_sizes, int n_in,
                              void* d_out, int out_size, void* d_ws, size_t ws_size,
                              hipStream_t stream) {
    const float* bond    = (const float*)d_in[0];
    const float* angle   = (const float*)d_in[1];
    const int*   species = (const int*)d_in[2];
    const int*   nbr     = (const int*)d_in[3];
    const int*   crys    = (const int*)d_in[4];
    const float* W1b_rel = (const float*)d_in[5];
    const float* W1b_root= (const float*)d_in[6];
    const float* b1b     = (const float*)d_in[7];
    const float* W1a_rel = (const float*)d_in[8];
    const float* W1a_root= (const float*)d_in[9];
    const float* b1a     = (const float*)d_in[10];
    const float* W2b_rel = (const float*)d_in[11];
    const float* W2b_root= (const float*)d_in[12];
    const float* b2b     = (const float*)d_in[13];
    const float* W2a_rel = (const float*)d_in[14];
    const float* W2a_root= (const float*)d_in[15];
    const float* b2a     = (const float*)d_in[16];
    const float* fcW     = (const float*)d_in[17];
    const float* fcb     = (const float*)d_in[18];
    float* out = (float*)d_out;

    char* ws = (char*)d_ws;
    size_t off = 0;
    auto alloc = [&](size_t bytes) {
        char* p = ws + off;
        off = (off + bytes + 255) & ~(size_t)255;
        return p;
    };
    __bf16* Wp1b = (__bf16*)alloc((size_t)512 * 256 * 2);   // padded K 480->512
    __bf16* Wp1a = (__bf16*)alloc((size_t)2880 * 256 * 2);
    __bf16* Wp2b = (__bf16*)alloc((size_t)64 * 256 * 2);
    __bf16* Wp2a = (__bf16*)alloc((size_t)64 * 256 * 2);
    float*  bondT = (float*)alloc((size_t)16 * NNP * 4);    // padded rows 12->16
    float*  angleT= (float*)alloc((size_t)144 * NNP * 4);
    float*  Yb   = (float*)alloc((size_t)NN * 256 * 4);
    float*  Ya   = (float*)alloc((size_t)NN * 256 * 4);
    __bf16* Hbp  = (__bf16*)alloc((size_t)2 * MT2 * 512 * 2);
    __bf16* Hap  = (__bf16*)alloc((size_t)2 * MT2 * 512 * 2);
    int*    adj  = (int*)alloc((size_t)NN * 64 * 4);
    int*    deg  = (int*)alloc((size_t)NN * 4);
    float*  pooled = (float*)alloc((size_t)NCRYS * NSUB * 128 * 4);

    hipMemsetAsync(deg, 0, (size_t)NN * 4, stream);
    hipMemsetAsync(pooled, 0, (size_t)NCRYS * NSUB * 128 * 4, stream);
    hipMemsetAsync(Wp1b, 0, (size_t)512 * 256 * 2, stream);   // zero K-pad tail
    hipMemsetAsync(bondT, 0, (size_t)16 * NNP * 4, stream);   // zero pad rows

    setup_kernel<<<1822, 256, 0, stream>>>(species, nbr, adj, deg,
                                           W1b_rel, W1b_root, W1a_rel, W1a_root,
                                           W2b_rel, W2b_root, W2a_rel, W2a_root,
                                           Wp1b, Wp1a, Wp2b, Wp2a,
                                           bond, angle, bondT, angleT);

    mega_gemm1<<<628, 512, 0, stream>>>(bondT, angleT, Wp1b, Wp1a, Yb, Ya);
    agg_packed<<<dim3(5024, 2), 256, 0, stream>>>(Yb, Ya, adj, deg, b1b, b1a, Hbp, Hap);
    mega_gemm2<<<dim3(314, 2), 256, 0, stream>>>(Hbp, Hap, Wp2b, Wp2a, Yb, Ya);
    agg_pool<<<dim3(5000, 2), 256, 0, stream>>>(Yb, Ya, adj, deg, b2b, b2a, crys, pooled);
    final2<<<NCRYS * 2, 64, 0, stream>>>(pooled, crys, fcW, fcb, out);
}